// Round 2
// baseline (1107.846 us; speedup 1.0000x reference)
//
#include <hip/hip_runtime.h>
#include <hip/hip_bf16.h>

typedef __bf16 bf16x8 __attribute__((ext_vector_type(8)));
typedef float f32x4 __attribute__((ext_vector_type(4)));

#define B_ 4
#define N_ 512
#define D_ 128
#define H_ 8
#define LSTR 264  // LDS row stride (elems): 528B rows, 16B-aligned

__device__ __forceinline__ unsigned short f2bf(float f) {
    // round-to-nearest-even f32 -> bf16 bits (inputs are normal floats)
    unsigned int u = __float_as_uint(f);
    unsigned int r = (u + 0x7FFFu + ((u >> 16) & 1u)) >> 16;
    return (unsigned short)r;
}

// ---------------- Kernel A: per-node precomputation (all f32) ----------------
// values = node@m_w+m_b, skip = node@skip_w+skip_b,
// combo = node@w2_w+w2_b + graph@wg_w+wg_b + w1_b + we_b
__global__ __launch_bounds__(128) void prep_kernel(
    const float* __restrict__ node,
    const float* __restrict__ graph,
    const float* __restrict__ m_w, const float* __restrict__ m_b,
    const float* __restrict__ skip_w, const float* __restrict__ skip_b,
    const float* __restrict__ w1_b,
    const float* __restrict__ w2_w, const float* __restrict__ w2_b,
    const float* __restrict__ we_b,
    const float* __restrict__ wg_w, const float* __restrict__ wg_b,
    float* __restrict__ values_ws,
    float* __restrict__ combo_ws,
    float* __restrict__ skip_ws)
{
    __shared__ float s_node[4][D_];
    __shared__ float s_graph[D_];
    const int col = threadIdx.x;
    const int b  = blockIdx.x >> 7;         // 512 blocks = 4 b * 128 rowgroups
    const int n0 = (blockIdx.x & 127) * 4;

    for (int r = 0; r < 4; ++r)
        s_node[r][col] = node[(size_t)(b * N_ + n0 + r) * D_ + col];
    s_graph[col] = graph[b * D_ + col];
    __syncthreads();

    float gacc = 0.f;
#pragma unroll 8
    for (int k = 0; k < D_; ++k)
        gacc += s_graph[k] * wg_w[k * D_ + col];
    const float cbase = gacc + wg_b[col] + w1_b[col] + we_b[col] + w2_b[col];

    for (int r = 0; r < 4; ++r) {
        float v = 0.f, s = 0.f, c = 0.f;
#pragma unroll 8
        for (int k = 0; k < D_; ++k) {
            const float nf = s_node[r][k];
            v += nf * m_w[k * D_ + col];
            s += nf * skip_w[k * D_ + col];
            c += nf * w2_w[k * D_ + col];
        }
        const size_t row = (size_t)(b * N_ + n0 + r) * D_ + col;
        values_ws[row] = v + m_b[col];
        skip_ws[row]   = s + skip_b[col];
        combo_ws[row]  = c + cbase;
    }
}

// ---------------- Kernel B: fused GATv2 per (b, i) ----------------
__global__ __launch_bounds__(256, 3) void gat_kernel(
    const float* __restrict__ edge,
    const float* __restrict__ node,
    const float* __restrict__ adj,
    const float* __restrict__ we_w,
    const float* __restrict__ w1_w,
    const float* __restrict__ a_w,
    const float* __restrict__ a_b,
    const float* __restrict__ ln_scale,
    const float* __restrict__ ln_offset,
    const float* __restrict__ values_ws,
    const float* __restrict__ combo_ws,
    const float* __restrict__ skip_ws,
    float* __restrict__ out)
{
    __shared__ __align__(16) unsigned short sA[64 * LSTR];  // bf16 [edge(128)|node(128)] per j-row
    __shared__ float sLogit[H_ * N_];
    __shared__ float sBias[N_];
    __shared__ float sPart[2 * D_];
    __shared__ float sRed[4];

    const int tid  = threadIdx.x;
    const int wave = tid >> 6;
    const int lane = tid & 63;
    const int quad = lane >> 4;
    const int mm   = lane & 15;

    const int b = blockIdx.x >> 9;
    const int i = blockIdx.x & (N_ - 1);

    // adjacency bias row (receiver i fixed, over senders j)
    for (int j = tid; j < N_; j += 256)
        sBias[j] = (adj[(size_t)(b * N_ + i) * N_ + j] - 1.0f) * 1e9f;

    // B-fragments in registers: wave owns heads h0, h0+1 (MID cols h*16..h*16+15)
    // B layout (16x16x32): lane holds B[k = kc*32 + quad*8 + t][n = lane&15]
    const int h0 = wave * 2;
    bf16x8 breg[2][8];
#pragma unroll
    for (int nti = 0; nti < 2; ++nti) {
        const int n = (h0 + nti) * 16 + mm;
#pragma unroll
        for (int kc = 0; kc < 8; ++kc) {
            union { unsigned short u[8]; bf16x8 v; } t;
#pragma unroll
            for (int e = 0; e < 8; ++e) {
                const int k = kc * 32 + quad * 8 + e;
                const float w = (k < 128) ? we_w[k * D_ + n] : w1_w[(k - 128) * D_ + n];
                t.u[e] = f2bf(w);
            }
            breg[nti][kc] = t.v;
        }
    }

    float creg[2], awreg[2], abreg[2];
#pragma unroll
    for (int nti = 0; nti < 2; ++nti) {
        creg[nti]  = combo_ws[(size_t)(b * N_ + i) * D_ + (h0 + nti) * 16 + mm];
        awreg[nti] = a_w[(h0 + nti) * 16 + mm];
        abreg[nti] = a_b[h0 + nti];
    }

    const size_t edge_base = (size_t)(b * N_ + i) * N_ * D_;
    const size_t node_base = (size_t)b * N_ * D_;

    for (int pass = 0; pass < 8; ++pass) {
        const int j0 = pass * 64;
        __syncthreads();
        // stage 64 rows x [edge|node] as bf16: each chunk = 8 consecutive floats -> 8 bf16
        for (int c = tid; c < 2048; c += 256) {
            const int row  = c >> 5;
            const int part = c & 31;   // 0..15 edge chunk, 16..31 node chunk (constant per thread)
            const float* src = (part < 16)
                ? (edge + edge_base + (size_t)(j0 + row) * D_ + part * 8)
                : (node + node_base + (size_t)(j0 + row) * D_ + (part - 16) * 8);
            const float4 f0 = ((const float4*)src)[0];
            const float4 f1 = ((const float4*)src)[1];
            uint4 w;
            w.x = (unsigned)f2bf(f0.x) | ((unsigned)f2bf(f0.y) << 16);
            w.y = (unsigned)f2bf(f0.z) | ((unsigned)f2bf(f0.w) << 16);
            w.z = (unsigned)f2bf(f1.x) | ((unsigned)f2bf(f1.y) << 16);
            w.w = (unsigned)f2bf(f1.z) | ((unsigned)f2bf(f1.w) << 16);
            ((uint4*)sA)[row * 33 + part] = w;
        }
        __syncthreads();

        f32x4 acc[4][2];
#pragma unroll
        for (int mt = 0; mt < 4; ++mt)
#pragma unroll
            for (int nti = 0; nti < 2; ++nti) {
                f32x4 z = {0.f, 0.f, 0.f, 0.f};
                acc[mt][nti] = z;
            }

#pragma unroll
        for (int kc = 0; kc < 8; ++kc) {
            bf16x8 a[4];
#pragma unroll
            for (int mt = 0; mt < 4; ++mt)  // A: lane holds A[m=lane&15][k=quad*8+t]
                a[mt] = *(const bf16x8*)(sA + (mt * 16 + mm) * LSTR + kc * 32 + quad * 8);
#pragma unroll
            for (int mt = 0; mt < 4; ++mt)
#pragma unroll
                for (int nti = 0; nti < 2; ++nti)
                    acc[mt][nti] = __builtin_amdgcn_mfma_f32_16x16x32_bf16(
                        a[mt], breg[nti][kc], acc[mt][nti], 0, 0, 0);
        }

        // epilogue: +combo, leaky_relu, *a_w, reduce 16 cols -> logit
        // C/D: lane reg r = D[row=quad*4+r][col=lane&15]
#pragma unroll
        for (int mt = 0; mt < 4; ++mt)
#pragma unroll
            for (int nti = 0; nti < 2; ++nti)
#pragma unroll
                for (int r = 0; r < 4; ++r) {
                    float v = acc[mt][nti][r] + creg[nti];
                    v = v > 0.f ? v : 0.01f * v;
                    float p = v * awreg[nti];
                    p += __shfl_xor(p, 1);
                    p += __shfl_xor(p, 2);
                    p += __shfl_xor(p, 4);
                    p += __shfl_xor(p, 8);
                    if (mm == 0) {
                        const int j = j0 + mt * 16 + quad * 4 + r;
                        sLogit[(h0 + nti) * N_ + j] = p + abreg[nti] + sBias[j];
                    }
                }
    }
    __syncthreads();

    // softmax over j, per head (wave handles its 2 heads)
#pragma unroll
    for (int hi = 0; hi < 2; ++hi) {
        float* lrow = sLogit + (h0 + hi) * N_;
        float v[8];
        float mx = -3.0e38f;
#pragma unroll
        for (int t = 0; t < 8; ++t) { v[t] = lrow[lane + t * 64]; mx = fmaxf(mx, v[t]); }
#pragma unroll
        for (int s = 1; s < 64; s <<= 1) mx = fmaxf(mx, __shfl_xor(mx, s));
        float sum = 0.f;
#pragma unroll
        for (int t = 0; t < 8; ++t) { v[t] = __expf(v[t] - mx); sum += v[t]; }
#pragma unroll
        for (int s = 1; s < 64; s <<= 1) sum += __shfl_xor(sum, s);
        const float inv = 1.0f / sum;
#pragma unroll
        for (int t = 0; t < 8; ++t) lrow[lane + t * 64] = v[t] * inv;
    }
    __syncthreads();

    // AV: out[m] = sum_j coef[m>>4][j] * values[b][j][m]
    const int m = tid & 127;
    const int half = tid >> 7;
    const float* crow = sLogit + (m >> 4) * N_;
    const float* vp = values_ws + (size_t)b * N_ * D_ + m;
    float av = 0.f;
    for (int j = half; j < N_; j += 2)
        av += crow[j] * vp[(size_t)j * D_];
    sPart[half * D_ + m] = av;
    __syncthreads();

    float r = 0.f;
    if (tid < 128) {
        r = sPart[m] + sPart[D_ + m] + skip_ws[(size_t)(b * N_ + i) * D_ + m];
        r = fmaxf(r, 0.f);
        float s1 = r, s2 = r * r;
#pragma unroll
        for (int s = 1; s < 64; s <<= 1) { s1 += __shfl_xor(s1, s); s2 += __shfl_xor(s2, s); }
        if (lane == 0) { sRed[wave * 2] = s1; sRed[wave * 2 + 1] = s2; }
    }
    __syncthreads();
    if (tid < 128) {
        const float s1 = sRed[0] + sRed[2];
        const float s2 = sRed[1] + sRed[3];
        const float mu  = s1 * (1.0f / 128.0f);
        const float var = s2 * (1.0f / 128.0f) - mu * mu;
        const float o = (r - mu) * rsqrtf(var + 1e-5f) * ln_scale[m] + ln_offset[m];
        out[(size_t)(b * N_ + i) * D_ + m] = o;
    }
}

extern "C" void kernel_launch(void* const* d_in, const int* in_sizes, int n_in,
                              void* d_out, int out_size, void* d_ws, size_t ws_size,
                              hipStream_t stream) {
    const float* node   = (const float*)d_in[0];
    const float* edge   = (const float*)d_in[1];
    const float* graph  = (const float*)d_in[2];
    const float* adj    = (const float*)d_in[3];
    // d_in[4] hidden: unused by the reference
    const float* m_w    = (const float*)d_in[5];
    const float* m_b    = (const float*)d_in[6];
    const float* skip_w = (const float*)d_in[7];
    const float* skip_b = (const float*)d_in[8];
    const float* w1_w   = (const float*)d_in[9];
    const float* w1_b   = (const float*)d_in[10];
    const float* w2_w   = (const float*)d_in[11];
    const float* w2_b   = (const float*)d_in[12];
    const float* we_w   = (const float*)d_in[13];
    const float* we_b   = (const float*)d_in[14];
    const float* wg_w   = (const float*)d_in[15];
    const float* wg_b   = (const float*)d_in[16];
    const float* a_w    = (const float*)d_in[17];
    const float* a_b    = (const float*)d_in[18];
    const float* ln_s   = (const float*)d_in[19];
    const float* ln_o   = (const float*)d_in[20];

    char* ws = (char*)d_ws;
    float* values_ws = (float*)ws;                       // 1 MB
    float* combo_ws  = (float*)(ws + (1u << 20));        // 1 MB
    float* skip_ws   = (float*)(ws + (2u << 20));        // 1 MB

    hipLaunchKernelGGL(prep_kernel, dim3(512), dim3(128), 0, stream,
        node, graph, m_w, m_b, skip_w, skip_b, w1_b, w2_w, w2_b, we_b, wg_w, wg_b,
        values_ws, combo_ws, skip_ws);

    hipLaunchKernelGGL(gat_kernel, dim3(B_ * N_), dim3(256), 0, stream,
        edge, node, adj, we_w, w1_w, a_w, a_b, ln_s, ln_o,
        values_ws, combo_ws, skip_ws, (float*)d_out);
}